// Round 4
// baseline (6835.731 us; speedup 1.0000x reference)
//
#include <hip/hip_runtime.h>
#include <cstdint>
#include <climits>
#include <math.h>

#define NN 50000
#define EE 1600000
#define GG 512
#define NEG_SLOPE 0.2f
#define NB 196          // ceil(NN/256) scan blocks

// ---------- degree histogram ----------
__global__ void k_hist(const int* __restrict__ dst, int* __restrict__ hist) {
    int e = blockIdx.x * blockDim.x + threadIdx.x;
    if (e < EE) atomicAdd(&hist[dst[e]], 1);
}

// ---------- CSR build: scan of hist then scatter (real edges only) ----------
__global__ void k_scan_a(const int* __restrict__ hist, int* __restrict__ bsum) {
    __shared__ int tmp[256];
    int i = blockIdx.x * 256 + threadIdx.x;
    tmp[threadIdx.x] = (i < NN) ? hist[i] : 0;
    __syncthreads();
    for (int d = 128; d; d >>= 1) {
        if (threadIdx.x < d) tmp[threadIdx.x] += tmp[threadIdx.x + d];
        __syncthreads();
    }
    if (threadIdx.x == 0) bsum[blockIdx.x] = tmp[0];
}

__global__ void k_scan_b(int* __restrict__ bsum, int* __restrict__ rowptr) {
    int acc = 0;
    for (int b = 0; b < NB; b++) { int v = bsum[b]; bsum[b] = acc; acc += v; }
    rowptr[NN] = acc;  // == EE
}

__global__ void k_scan_c(const int* __restrict__ hist, const int* __restrict__ bsum,
                         int* __restrict__ rowptr) {
    __shared__ int tmp[256];
    int i = blockIdx.x * 256 + threadIdx.x;
    int v = (i < NN) ? hist[i] : 0;
    tmp[threadIdx.x] = v;
    __syncthreads();
    for (int d = 1; d < 256; d <<= 1) {
        int t = (threadIdx.x >= d) ? tmp[threadIdx.x - d] : 0;
        __syncthreads();
        tmp[threadIdx.x] += t;
        __syncthreads();
    }
    if (i < NN) rowptr[i] = tmp[threadIdx.x] - v + bsum[blockIdx.x];
}

__global__ void k_cursor_init(const int* __restrict__ rowptr, int* __restrict__ cursor) {
    int i = blockIdx.x * blockDim.x + threadIdx.x;
    if (i < NN) cursor[i] = rowptr[i];
}

__global__ void k_scatter(const int* __restrict__ dst, int* __restrict__ cursor,
                          int* __restrict__ csr_eid) {
    int e = blockIdx.x * blockDim.x + threadIdx.x;
    if (e < EE) {
        int p = atomicAdd(&cursor[dst[e]], 1);
        csr_eid[p] = e;
    }
}

// ---------- fused dual node-linear: xl = X@Wl+bl ; xr = X@Wr+br ----------
__global__ void k_dual_linear(const float* __restrict__ X,
                              const float* __restrict__ Wl, const float* __restrict__ bl,
                              const float* __restrict__ Wr, const float* __restrict__ br,
                              float* __restrict__ xl, float* __restrict__ xr,
                              int Cin, int Cout) {
    int t = blockIdx.x * blockDim.x + threadIdx.x;
    if (t >= NN * Cout) return;
    int i = t / Cout, j = t - i * Cout;
    const float* xrow = X + (size_t)i * Cin;
    float al = bl[j], ar = br[j];
    for (int k = 0; k < Cin; k++) {
        float xv = xrow[k];
        al += xv * Wl[k * Cout + j];
        ar += xv * Wr[k * Cout + j];
    }
    xl[t] = al;
    xr[t] = ar;
}

// ---------- fused per-dst-node: scores + online softmax + aggregate ----------
// Wave per node. Lane l (< C/VEC) owns channels [l*VEC, l*VEC+VEC).
// We columns in VGPRs; edge index wave-uniform (scalar pipe).
// Self-loop: edge-attr = mean of incoming ea  =>  mean of per-edge ea@We
// (accumulated in wsum), processed last; no loop_ea materialization.
template <int C, int VEC, int RELU>
__global__ void k_fused_node(const int* __restrict__ rowptr, const int* __restrict__ csr_eid,
                             const int* __restrict__ srcv, const float* __restrict__ ea,
                             const float* __restrict__ We, const float* __restrict__ att,
                             const float* __restrict__ xl, const float* __restrict__ xr,
                             const float* __restrict__ bias, float* __restrict__ out) {
    constexpr int NL = C / VEC;
    const int lane = threadIdx.x & 63;
    int wid = blockIdx.x * (blockDim.x >> 6) + (threadIdx.x >> 6);
    int nw = gridDim.x * (blockDim.x >> 6);
    const bool act = lane < NL;

    float Wf[18][VEC], af[VEC], bv[VEC];
    if (act) {
#pragma unroll
        for (int k = 0; k < 18; k++)
#pragma unroll
            for (int j = 0; j < VEC; j++) Wf[k][j] = We[k * C + lane * VEC + j];
#pragma unroll
        for (int j = 0; j < VEC; j++) { af[j] = att[lane * VEC + j]; bv[j] = bias[lane * VEC + j]; }
    }

    for (int i = wid; i < NN; i += nw) {
        int beg = __builtin_amdgcn_readfirstlane(rowptr[i]);
        int end = __builtin_amdgcn_readfirstlane(rowptr[i + 1]);

        float xlv[VEC], xrv[VEC];
        if (act) {
            if constexpr (VEC == 4) {
                float4 a = *(const float4*)(xl + (size_t)i * C + lane * 4);
                xlv[0] = a.x; xlv[1] = a.y; xlv[2] = a.z; xlv[3] = a.w;
                float4 b = *(const float4*)(xr + (size_t)i * C + lane * 4);
                xrv[0] = b.x; xrv[1] = b.y; xrv[2] = b.z; xrv[3] = b.w;
            } else {
                float2 a = *(const float2*)(xl + (size_t)i * C + lane * 2);
                xlv[0] = a.x; xlv[1] = a.y;
                float2 b = *(const float2*)(xr + (size_t)i * C + lane * 2);
                xrv[0] = b.x; xrv[1] = b.y;
            }
        } else {
#pragma unroll
            for (int j = 0; j < VEC; j++) { xlv[j] = 0.f; xrv[j] = 0.f; }
        }

        float m = -INFINITY, zs = 0.0f;
        float acc[VEC], wsum[VEC];
#pragma unroll
        for (int j = 0; j < VEC; j++) { acc[j] = 0.f; wsum[j] = 0.f; }

        // software pipeline: one-edge-ahead prefetch of (eid -> src -> ea row, xl row)
        int sI_n = 0;
        float ee_n[18], xv_n[VEC];
        if (beg < end) {
            int eidn = __builtin_amdgcn_readfirstlane(csr_eid[beg]);
            sI_n = __builtin_amdgcn_readfirstlane(srcv[eidn]);
#pragma unroll
            for (int k = 0; k < 18; k++) ee_n[k] = ea[(size_t)eidn * 18 + k];
            if (act) {
                if constexpr (VEC == 4) {
                    float4 v = *(const float4*)(xl + (size_t)sI_n * C + lane * 4);
                    xv_n[0] = v.x; xv_n[1] = v.y; xv_n[2] = v.z; xv_n[3] = v.w;
                } else {
                    float2 v = *(const float2*)(xl + (size_t)sI_n * C + lane * 2);
                    xv_n[0] = v.x; xv_n[1] = v.y;
                }
            }
        }

        for (int p = beg; p < end; p++) {
            float ee[18], xv[VEC];
#pragma unroll
            for (int k = 0; k < 18; k++) ee[k] = ee_n[k];
#pragma unroll
            for (int j = 0; j < VEC; j++) xv[j] = xv_n[j];

            if (p + 1 < end) {
                int eidn = __builtin_amdgcn_readfirstlane(csr_eid[p + 1]);
                sI_n = __builtin_amdgcn_readfirstlane(srcv[eidn]);
#pragma unroll
                for (int k = 0; k < 18; k++) ee_n[k] = ea[(size_t)eidn * 18 + k];
                if (act) {
                    if constexpr (VEC == 4) {
                        float4 v = *(const float4*)(xl + (size_t)sI_n * C + lane * 4);
                        xv_n[0] = v.x; xv_n[1] = v.y; xv_n[2] = v.z; xv_n[3] = v.w;
                    } else {
                        float2 v = *(const float2*)(xl + (size_t)sI_n * C + lane * 2);
                        xv_n[0] = v.x; xv_n[1] = v.y;
                    }
                }
            }

            float part = 0.0f;
            if (act) {
#pragma unroll
                for (int j = 0; j < VEC; j++) {
                    float w = 0.0f;
#pragma unroll
                    for (int k = 0; k < 18; k++) w += ee[k] * Wf[k][j];
                    wsum[j] += w;
                    float u = xv[j] + xrv[j] + w;
                    float h = u > 0.0f ? u : NEG_SLOPE * u;
                    part += af[j] * h;
                }
            }
#pragma unroll
            for (int off = 32; off; off >>= 1) part += __shfl_xor(part, off, 64);

            float mn = fmaxf(m, part);
            float sc = __expf(m - mn);
            float pe = __expf(part - mn);
            zs = zs * sc + pe;
            m = mn;
            if (act) {
#pragma unroll
                for (int j = 0; j < VEC; j++) acc[j] = acc[j] * sc + pe * xv[j];
            }
        }

        // self-loop (processed last; order-invariant under online softmax)
        {
            float rdeg = (end > beg) ? 1.0f / (float)(end - beg) : 1.0f;
            float part = 0.0f;
            if (act) {
#pragma unroll
                for (int j = 0; j < VEC; j++) {
                    float u = xlv[j] + xrv[j] + wsum[j] * rdeg;
                    float h = u > 0.0f ? u : NEG_SLOPE * u;
                    part += af[j] * h;
                }
            }
#pragma unroll
            for (int off = 32; off; off >>= 1) part += __shfl_xor(part, off, 64);

            float mn = fmaxf(m, part);
            float sc = __expf(m - mn);
            float pe = __expf(part - mn);
            zs = zs * sc + pe;
            if (act) {
#pragma unroll
                for (int j = 0; j < VEC; j++) acc[j] = acc[j] * sc + pe * xlv[j];
            }
        }

        float rz = 1.0f / zs;
        if (act) {
            float o[VEC];
#pragma unroll
            for (int j = 0; j < VEC; j++) {
                o[j] = acc[j] * rz + bv[j];
                if (RELU) o[j] = fmaxf(o[j], 0.0f);
            }
            if constexpr (VEC == 4) {
                *(float4*)(out + (size_t)i * C + lane * 4) = make_float4(o[0], o[1], o[2], o[3]);
            } else {
                *(float2*)(out + (size_t)i * C + lane * 2) = make_float2(o[0], o[1]);
            }
        }
    }
}

// ---------- mean pooling per graph (batch_ids sorted); relu folded in ----------
__global__ void k_pool(const float* __restrict__ h, const int* __restrict__ batch,
                       float* __restrict__ pooled) {
    int g = blockIdx.x;
    int lo = 0, hi = NN;
    while (lo < hi) { int mid = (lo + hi) >> 1; if (batch[mid] < g) lo = mid + 1; else hi = mid; }
    int start = lo;
    lo = start; hi = NN;
    while (lo < hi) { int mid = (lo + hi) >> 1; if (batch[mid] < g + 1) lo = mid + 1; else hi = mid; }
    int end = lo;
    float cnt = (float)(end - start);
    int c = threadIdx.x;
    if (c < 200) {
        float acc = 0.0f;
        for (int i = start; i < end; i++) acc += fmaxf(h[(size_t)i * 200 + c], 0.0f);
        pooled[g * 200 + c] = acc / fmaxf(cnt, 1.0f);
    }
}

// ---------- small dense layers on [G, *] ----------
__global__ void k_mlp(const float* __restrict__ X, const float* __restrict__ W,
                      const float* __restrict__ b, float* __restrict__ Y,
                      int Cin, int Cout, int do_relu) {
    int t = blockIdx.x * blockDim.x + threadIdx.x;
    if (t >= GG * Cout) return;
    int g = t / Cout, j = t - g * Cout;
    const float* xrow = X + (size_t)g * Cin;
    float acc = b[j];
    for (int k = 0; k < Cin; k++) acc += xrow[k] * W[k * Cout + j];
    if (do_relu) acc = fmaxf(acc, 0.0f);
    Y[t] = acc;
}

extern "C" void kernel_launch(void* const* d_in, const int* in_sizes, int n_in,
                              void* d_out, int out_size, void* d_ws, size_t ws_size,
                              hipStream_t stream) {
    const float* x   = (const float*)d_in[0];
    const int*   ei  = (const int*)d_in[1];
    const float* ea  = (const float*)d_in[2];
    const int*   bat = (const int*)d_in[3];
    const float* W1l = (const float*)d_in[4];  const float* b1l = (const float*)d_in[5];
    const float* W1r = (const float*)d_in[6];  const float* b1r = (const float*)d_in[7];
    const float* W1e = (const float*)d_in[8];
    const float* a1  = (const float*)d_in[9];  const float* c1  = (const float*)d_in[10];
    const float* W2l = (const float*)d_in[11]; const float* b2l = (const float*)d_in[12];
    const float* W2r = (const float*)d_in[13]; const float* b2r = (const float*)d_in[14];
    const float* W2e = (const float*)d_in[15];
    const float* a2  = (const float*)d_in[16]; const float* c2  = (const float*)d_in[17];
    const float* W3  = (const float*)d_in[18]; const float* b3  = (const float*)d_in[19];
    const float* F1  = (const float*)d_in[20]; const float* bf1 = (const float*)d_in[21];
    const float* F2  = (const float*)d_in[22]; const float* bf2 = (const float*)d_in[23];
    const float* F3  = (const float*)d_in[24]; const float* bf3 = (const float*)d_in[25];

    const int* srcv = ei;        // edge_index[0]
    const int* dstv = ei + EE;   // edge_index[1]

    float* W = (float*)d_ws;
    size_t off = 0;
    int*   hist    = (int*)(W + off); off += NN;
    float* xl      = W + off; off += (size_t)NN * 200;
    float* xr      = W + off; off += (size_t)NN * 200;
    float* h1      = W + off; off += (size_t)NN * 100;
    float* h2      = W + off; off += (size_t)NN * 200;
    int*   rowptr  = (int*)(W + off); off += NN + 4;
    int*   cursor  = (int*)(W + off); off += NN;
    int*   csr_eid = (int*)(W + off); off += EE;
    int*   bsum    = (int*)(W + off); off += 256;
    float* pooled  = W + off; off += (size_t)GG * 200;
    float* p400    = W + off; off += (size_t)GG * 400;
    float* y1      = W + off; off += (size_t)GG * 200;
    float* y2      = W + off; off += (size_t)GG * 100;
    (void)ws_size; (void)n_in; (void)in_sizes; (void)out_size;

    const int B = 256;
    const int NODEB = 12500;   // 4 waves/block -> 50000 waves, 1 node each

    // ---- degree histogram + CSR by dst (real edges only) ----
    hipMemsetAsync(hist, 0, (size_t)NN * sizeof(int), stream);
    k_hist<<<(EE + B - 1) / B, B, 0, stream>>>(dstv, hist);
    k_scan_a<<<NB, 256, 0, stream>>>(hist, bsum);
    k_scan_b<<<1, 1, 0, stream>>>(bsum, rowptr);
    k_scan_c<<<NB, 256, 0, stream>>>(hist, bsum, rowptr);
    k_cursor_init<<<(NN + B - 1) / B, B, 0, stream>>>(rowptr, cursor);
    k_scatter<<<(EE + B - 1) / B, B, 0, stream>>>(dstv, cursor, csr_eid);

    // ---- GAT layer 1: 16 -> 100 ----
    k_dual_linear<<<((size_t)NN * 100 + B - 1) / B, B, 0, stream>>>(x, W1l, b1l, W1r, b1r, xl, xr, 16, 100);
    k_fused_node<100, 2, 1><<<NODEB, B, 0, stream>>>(rowptr, csr_eid, srcv, ea, W1e, a1, xl, xr, c1, h1);

    // ---- GAT layer 2: 100 -> 200 ----
    k_dual_linear<<<((size_t)NN * 200 + B - 1) / B, B, 0, stream>>>(h1, W2l, b2l, W2r, b2r, xl, xr, 100, 200);
    k_fused_node<200, 4, 0><<<NODEB, B, 0, stream>>>(rowptr, csr_eid, srcv, ea, W2e, a2, xl, xr, c2, h2);

    // ---- pool (mean over graph, relu fused) then W3 + FFN ----
    k_pool<<<GG, 256, 0, stream>>>(h2, bat, pooled);
    k_mlp<<<(GG * 400 + B - 1) / B, B, 0, stream>>>(pooled, W3, b3, p400, 200, 400, 0);
    k_mlp<<<(GG * 200 + B - 1) / B, B, 0, stream>>>(p400, F1, bf1, y1, 400, 200, 1);
    k_mlp<<<(GG * 100 + B - 1) / B, B, 0, stream>>>(y1, F2, bf2, y2, 200, 100, 1);
    k_mlp<<<(GG * 100 + B - 1) / B, B, 0, stream>>>(y2, F3, bf3, (float*)d_out, 100, 100, 0);
}

// Round 5
// 2230.004 us; speedup vs baseline: 3.0653x; 3.0653x over previous
//
#include <hip/hip_runtime.h>
#include <cstdint>
#include <climits>
#include <math.h>

#define NN 50000
#define EE 1600000
#define GG 512
#define NEG_SLOPE 0.2f
#define NB 196          // ceil(NN/256) scan blocks

__device__ __forceinline__ float rfl(float v) {
    return __int_as_float(__builtin_amdgcn_readfirstlane(__float_as_int(v)));
}

// ---------- degree histogram ----------
__global__ void k_hist(const int* __restrict__ dst, int* __restrict__ hist) {
    int e = blockIdx.x * blockDim.x + threadIdx.x;
    if (e < EE) atomicAdd(&hist[dst[e]], 1);
}

// ---------- CSR build: scan of hist then scatter (real edges only) ----------
__global__ void k_scan_a(const int* __restrict__ hist, int* __restrict__ bsum) {
    __shared__ int tmp[256];
    int i = blockIdx.x * 256 + threadIdx.x;
    tmp[threadIdx.x] = (i < NN) ? hist[i] : 0;
    __syncthreads();
    for (int d = 128; d; d >>= 1) {
        if (threadIdx.x < d) tmp[threadIdx.x] += tmp[threadIdx.x + d];
        __syncthreads();
    }
    if (threadIdx.x == 0) bsum[blockIdx.x] = tmp[0];
}

__global__ void k_scan_b(int* __restrict__ bsum, int* __restrict__ rowptr) {
    int acc = 0;
    for (int b = 0; b < NB; b++) { int v = bsum[b]; bsum[b] = acc; acc += v; }
    rowptr[NN] = acc;  // == EE
}

__global__ void k_scan_c(const int* __restrict__ hist, const int* __restrict__ bsum,
                         int* __restrict__ rowptr) {
    __shared__ int tmp[256];
    int i = blockIdx.x * 256 + threadIdx.x;
    int v = (i < NN) ? hist[i] : 0;
    tmp[threadIdx.x] = v;
    __syncthreads();
    for (int d = 1; d < 256; d <<= 1) {
        int t = (threadIdx.x >= d) ? tmp[threadIdx.x - d] : 0;
        __syncthreads();
        tmp[threadIdx.x] += t;
        __syncthreads();
    }
    if (i < NN) rowptr[i] = tmp[threadIdx.x] - v + bsum[blockIdx.x];
}

__global__ void k_cursor_init(const int* __restrict__ rowptr, int* __restrict__ cursor) {
    int i = blockIdx.x * blockDim.x + threadIdx.x;
    if (i < NN) cursor[i] = rowptr[i];
}

__global__ void k_scatter(const int* __restrict__ dst, int* __restrict__ cursor,
                          int* __restrict__ csr_eid) {
    int e = blockIdx.x * blockDim.x + threadIdx.x;
    if (e < EE) {
        int p = atomicAdd(&cursor[dst[e]], 1);
        csr_eid[p] = e;
    }
}

// ---------- fused dual node-linear: xl = X@Wl+bl ; xr = X@Wr+br ----------
__global__ void k_dual_linear(const float* __restrict__ X,
                              const float* __restrict__ Wl, const float* __restrict__ bl,
                              const float* __restrict__ Wr, const float* __restrict__ br,
                              float* __restrict__ xl, float* __restrict__ xr,
                              int Cin, int Cout) {
    int t = blockIdx.x * blockDim.x + threadIdx.x;
    if (t >= NN * Cout) return;
    int i = t / Cout, j = t - i * Cout;
    const float* xrow = X + (size_t)i * Cin;
    float al = bl[j], ar = br[j];
    for (int k = 0; k < Cin; k++) {
        float xv = xrow[k];
        al += xv * Wl[k * Cout + j];
        ar += xv * Wr[k * Cout + j];
    }
    xl[t] = al;
    xr[t] = ar;
}

// ---------- fused per-dst-node: scores + online softmax + aggregate ----------
// Wave per node. Lane l (< C/VEC) owns channels [l*VEC, l*VEC+VEC).
// We columns in VGPRs; edge-attr row in SGPRs (readfirstlane of uniform loads).
// Self-loop edge-attr = mean of incoming ea -> mean of per-edge ea@We (wsum).
template <int C, int VEC, int RELU>
__global__ void __launch_bounds__(256, 2)
k_fused_node(const int* __restrict__ rowptr, const int* __restrict__ csr_eid,
             const int* __restrict__ srcv, const float* __restrict__ ea,
             const float* __restrict__ We, const float* __restrict__ att,
             const float* __restrict__ xl, const float* __restrict__ xr,
             const float* __restrict__ bias, float* __restrict__ out) {
    constexpr int NL = C / VEC;
    const int lane = threadIdx.x & 63;
    int wid = blockIdx.x * (blockDim.x >> 6) + (threadIdx.x >> 6);
    int nw = gridDim.x * (blockDim.x >> 6);
    const bool act = lane < NL;

    float Wf[18][VEC], af[VEC], bv[VEC];
    if (act) {
#pragma unroll
        for (int k = 0; k < 18; k++)
#pragma unroll
            for (int j = 0; j < VEC; j++) Wf[k][j] = We[k * C + lane * VEC + j];
#pragma unroll
        for (int j = 0; j < VEC; j++) { af[j] = att[lane * VEC + j]; bv[j] = bias[lane * VEC + j]; }
    } else {
#pragma unroll
        for (int k = 0; k < 18; k++)
#pragma unroll
            for (int j = 0; j < VEC; j++) Wf[k][j] = 0.f;
#pragma unroll
        for (int j = 0; j < VEC; j++) { af[j] = 0.f; bv[j] = 0.f; }
    }

    for (int i = wid; i < NN; i += nw) {
        int beg = __builtin_amdgcn_readfirstlane(rowptr[i]);
        int end = __builtin_amdgcn_readfirstlane(rowptr[i + 1]);

        float xlv[VEC], xrv[VEC];
        if (act) {
            if constexpr (VEC == 4) {
                float4 a = *(const float4*)(xl + (size_t)i * C + lane * 4);
                xlv[0] = a.x; xlv[1] = a.y; xlv[2] = a.z; xlv[3] = a.w;
                float4 b = *(const float4*)(xr + (size_t)i * C + lane * 4);
                xrv[0] = b.x; xrv[1] = b.y; xrv[2] = b.z; xrv[3] = b.w;
            } else {
                float2 a = *(const float2*)(xl + (size_t)i * C + lane * 2);
                xlv[0] = a.x; xlv[1] = a.y;
                float2 b = *(const float2*)(xr + (size_t)i * C + lane * 2);
                xrv[0] = b.x; xrv[1] = b.y;
            }
        } else {
#pragma unroll
            for (int j = 0; j < VEC; j++) { xlv[j] = 0.f; xrv[j] = 0.f; }
        }

        float m = -INFINITY, zs = 0.0f;
        float acc[VEC], wsum[VEC];
#pragma unroll
        for (int j = 0; j < VEC; j++) { acc[j] = 0.f; wsum[j] = 0.f; }

        // pipeline: one-edge-ahead prefetch. es_n lives in SGPRs (uniform),
        // xv_n in VEC VGPRs, sI_n/eidn scalar.
        int sI_n = 0;
        float es_n[18];   // SGPRs via rfl()
        float xv_n[VEC];
#pragma unroll
        for (int j = 0; j < VEC; j++) xv_n[j] = 0.f;
        if (beg < end) {
            int eidn = __builtin_amdgcn_readfirstlane(csr_eid[beg]);
            sI_n = __builtin_amdgcn_readfirstlane(srcv[eidn]);
            const float* eap = ea + (size_t)eidn * 18;
#pragma unroll
            for (int k = 0; k < 9; k++) {
                float2 q = *(const float2*)(eap + 2 * k);
                es_n[2 * k] = rfl(q.x);
                es_n[2 * k + 1] = rfl(q.y);
            }
            if (act) {
                if constexpr (VEC == 4) {
                    float4 v = *(const float4*)(xl + (size_t)sI_n * C + lane * 4);
                    xv_n[0] = v.x; xv_n[1] = v.y; xv_n[2] = v.z; xv_n[3] = v.w;
                } else {
                    float2 v = *(const float2*)(xl + (size_t)sI_n * C + lane * 2);
                    xv_n[0] = v.x; xv_n[1] = v.y;
                }
            }
        }

        for (int p = beg; p < end; p++) {
            float es[18], xv[VEC];
#pragma unroll
            for (int k = 0; k < 18; k++) es[k] = es_n[k];   // SGPR copies
#pragma unroll
            for (int j = 0; j < VEC; j++) xv[j] = xv_n[j];

            if (p + 1 < end) {
                int eidn = __builtin_amdgcn_readfirstlane(csr_eid[p + 1]);
                sI_n = __builtin_amdgcn_readfirstlane(srcv[eidn]);
                const float* eap = ea + (size_t)eidn * 18;
#pragma unroll
                for (int k = 0; k < 9; k++) {
                    float2 q = *(const float2*)(eap + 2 * k);
                    es_n[2 * k] = rfl(q.x);
                    es_n[2 * k + 1] = rfl(q.y);
                }
                if (act) {
                    if constexpr (VEC == 4) {
                        float4 v = *(const float4*)(xl + (size_t)sI_n * C + lane * 4);
                        xv_n[0] = v.x; xv_n[1] = v.y; xv_n[2] = v.z; xv_n[3] = v.w;
                    } else {
                        float2 v = *(const float2*)(xl + (size_t)sI_n * C + lane * 2);
                        xv_n[0] = v.x; xv_n[1] = v.y;
                    }
                }
            }

            float part = 0.0f;
#pragma unroll
            for (int j = 0; j < VEC; j++) {
                float w = 0.0f;
#pragma unroll
                for (int k = 0; k < 18; k++) w += es[k] * Wf[k][j];
                wsum[j] += w;
                float u = xv[j] + xrv[j] + w;
                float h = u > 0.0f ? u : NEG_SLOPE * u;
                part += af[j] * h;
            }
#pragma unroll
            for (int off = 32; off; off >>= 1) part += __shfl_xor(part, off, 64);

            float mn = fmaxf(m, part);
            float sc = __expf(m - mn);
            float pe = __expf(part - mn);
            zs = zs * sc + pe;
            m = mn;
#pragma unroll
            for (int j = 0; j < VEC; j++) acc[j] = acc[j] * sc + pe * xv[j];
        }

        // self-loop (order-invariant under online softmax)
        {
            float rdeg = (end > beg) ? 1.0f / (float)(end - beg) : 1.0f;
            float part = 0.0f;
#pragma unroll
            for (int j = 0; j < VEC; j++) {
                float u = xlv[j] + xrv[j] + wsum[j] * rdeg;
                float h = u > 0.0f ? u : NEG_SLOPE * u;
                part += af[j] * h;
            }
#pragma unroll
            for (int off = 32; off; off >>= 1) part += __shfl_xor(part, off, 64);

            float mn = fmaxf(m, part);
            float sc = __expf(m - mn);
            float pe = __expf(part - mn);
            zs = zs * sc + pe;
#pragma unroll
            for (int j = 0; j < VEC; j++) acc[j] = acc[j] * sc + pe * xlv[j];
        }

        float rz = 1.0f / zs;
        if (act) {
            float o[VEC];
#pragma unroll
            for (int j = 0; j < VEC; j++) {
                o[j] = acc[j] * rz + bv[j];
                if (RELU) o[j] = fmaxf(o[j], 0.0f);
            }
            if constexpr (VEC == 4) {
                *(float4*)(out + (size_t)i * C + lane * 4) = make_float4(o[0], o[1], o[2], o[3]);
            } else {
                *(float2*)(out + (size_t)i * C + lane * 2) = make_float2(o[0], o[1]);
            }
        }
    }
}

// ---------- mean pooling per graph (batch_ids sorted); relu folded in ----------
__global__ void k_pool(const float* __restrict__ h, const int* __restrict__ batch,
                       float* __restrict__ pooled) {
    int g = blockIdx.x;
    int lo = 0, hi = NN;
    while (lo < hi) { int mid = (lo + hi) >> 1; if (batch[mid] < g) lo = mid + 1; else hi = mid; }
    int start = lo;
    lo = start; hi = NN;
    while (lo < hi) { int mid = (lo + hi) >> 1; if (batch[mid] < g + 1) lo = mid + 1; else hi = mid; }
    int end = lo;
    float cnt = (float)(end - start);
    int c = threadIdx.x;
    if (c < 200) {
        float acc = 0.0f;
        for (int i = start; i < end; i++) acc += fmaxf(h[(size_t)i * 200 + c], 0.0f);
        pooled[g * 200 + c] = acc / fmaxf(cnt, 1.0f);
    }
}

// ---------- small dense layers on [G, *] ----------
__global__ void k_mlp(const float* __restrict__ X, const float* __restrict__ W,
                      const float* __restrict__ b, float* __restrict__ Y,
                      int Cin, int Cout, int do_relu) {
    int t = blockIdx.x * blockDim.x + threadIdx.x;
    if (t >= GG * Cout) return;
    int g = t / Cout, j = t - g * Cout;
    const float* xrow = X + (size_t)g * Cin;
    float acc = b[j];
    for (int k = 0; k < Cin; k++) acc += xrow[k] * W[k * Cout + j];
    if (do_relu) acc = fmaxf(acc, 0.0f);
    Y[t] = acc;
}

extern "C" void kernel_launch(void* const* d_in, const int* in_sizes, int n_in,
                              void* d_out, int out_size, void* d_ws, size_t ws_size,
                              hipStream_t stream) {
    const float* x   = (const float*)d_in[0];
    const int*   ei  = (const int*)d_in[1];
    const float* ea  = (const float*)d_in[2];
    const int*   bat = (const int*)d_in[3];
    const float* W1l = (const float*)d_in[4];  const float* b1l = (const float*)d_in[5];
    const float* W1r = (const float*)d_in[6];  const float* b1r = (const float*)d_in[7];
    const float* W1e = (const float*)d_in[8];
    const float* a1  = (const float*)d_in[9];  const float* c1  = (const float*)d_in[10];
    const float* W2l = (const float*)d_in[11]; const float* b2l = (const float*)d_in[12];
    const float* W2r = (const float*)d_in[13]; const float* b2r = (const float*)d_in[14];
    const float* W2e = (const float*)d_in[15];
    const float* a2  = (const float*)d_in[16]; const float* c2  = (const float*)d_in[17];
    const float* W3  = (const float*)d_in[18]; const float* b3  = (const float*)d_in[19];
    const float* F1  = (const float*)d_in[20]; const float* bf1 = (const float*)d_in[21];
    const float* F2  = (const float*)d_in[22]; const float* bf2 = (const float*)d_in[23];
    const float* F3  = (const float*)d_in[24]; const float* bf3 = (const float*)d_in[25];

    const int* srcv = ei;        // edge_index[0]
    const int* dstv = ei + EE;   // edge_index[1]

    float* W = (float*)d_ws;
    size_t off = 0;
    int*   hist    = (int*)(W + off); off += NN;
    float* xl      = W + off; off += (size_t)NN * 200;
    float* xr      = W + off; off += (size_t)NN * 200;
    float* h1      = W + off; off += (size_t)NN * 100;
    float* h2      = W + off; off += (size_t)NN * 200;
    int*   rowptr  = (int*)(W + off); off += NN + 4;
    int*   cursor  = (int*)(W + off); off += NN;
    int*   csr_eid = (int*)(W + off); off += EE;
    int*   bsum    = (int*)(W + off); off += 256;
    float* pooled  = W + off; off += (size_t)GG * 200;
    float* p400    = W + off; off += (size_t)GG * 400;
    float* y1      = W + off; off += (size_t)GG * 200;
    float* y2      = W + off; off += (size_t)GG * 100;
    (void)ws_size; (void)n_in; (void)in_sizes; (void)out_size;

    const int B = 256;
    const int NODEB = 12500;   // 4 waves/block -> 50000 waves, 1 node each

    // ---- degree histogram + CSR by dst (real edges only) ----
    hipMemsetAsync(hist, 0, (size_t)NN * sizeof(int), stream);
    k_hist<<<(EE + B - 1) / B, B, 0, stream>>>(dstv, hist);
    k_scan_a<<<NB, 256, 0, stream>>>(hist, bsum);
    k_scan_b<<<1, 1, 0, stream>>>(bsum, rowptr);
    k_scan_c<<<NB, 256, 0, stream>>>(hist, bsum, rowptr);
    k_cursor_init<<<(NN + B - 1) / B, B, 0, stream>>>(rowptr, cursor);
    k_scatter<<<(EE + B - 1) / B, B, 0, stream>>>(dstv, cursor, csr_eid);

    // ---- GAT layer 1: 16 -> 100 ----
    k_dual_linear<<<((size_t)NN * 100 + B - 1) / B, B, 0, stream>>>(x, W1l, b1l, W1r, b1r, xl, xr, 16, 100);
    k_fused_node<100, 2, 1><<<NODEB, B, 0, stream>>>(rowptr, csr_eid, srcv, ea, W1e, a1, xl, xr, c1, h1);

    // ---- GAT layer 2: 100 -> 200 ----
    k_dual_linear<<<((size_t)NN * 200 + B - 1) / B, B, 0, stream>>>(h1, W2l, b2l, W2r, b2r, xl, xr, 100, 200);
    k_fused_node<200, 4, 0><<<NODEB, B, 0, stream>>>(rowptr, csr_eid, srcv, ea, W2e, a2, xl, xr, c2, h2);

    // ---- pool (mean over graph, relu fused) then W3 + FFN ----
    k_pool<<<GG, 256, 0, stream>>>(h2, bat, pooled);
    k_mlp<<<(GG * 400 + B - 1) / B, B, 0, stream>>>(pooled, W3, b3, p400, 200, 400, 0);
    k_mlp<<<(GG * 200 + B - 1) / B, B, 0, stream>>>(p400, F1, bf1, y1, 400, 200, 1);
    k_mlp<<<(GG * 100 + B - 1) / B, B, 0, stream>>>(y1, F2, bf2, y2, 200, 100, 1);
    k_mlp<<<(GG * 100 + B - 1) / B, B, 0, stream>>>(y2, F3, bf3, (float*)d_out, 100, 100, 0);
}

// Round 6
// 1945.378 us; speedup vs baseline: 3.5138x; 1.1463x over previous
//
#include <hip/hip_runtime.h>
#include <cstdint>
#include <climits>
#include <math.h>

#define NN 50000
#define EE 1600000
#define GG 512
#define NEG_SLOPE 0.2f
#define NB 196          // ceil(NN/256) scan blocks
#define EAW 12          // padded dwords per packed-fp16 ea row (48 B, 16B-aligned)

typedef _Float16 half2v __attribute__((ext_vector_type(2)));

__device__ __forceinline__ float rfl(float v) {
    return __int_as_float(__builtin_amdgcn_readfirstlane(__float_as_int(v)));
}
__device__ __forceinline__ uint32_t packh2(float a, float b) {
    union { half2v h; uint32_t u; } c;
    c.h = half2v{(_Float16)a, (_Float16)b};
    return c.u;
}
__device__ __forceinline__ float fdot2u(uint32_t a, uint32_t b, float c) {
    union { uint32_t u; half2v h; } ua, ub;
    ua.u = a; ub.u = b;
    return __builtin_amdgcn_fdot2(ua.h, ub.h, c, false);
}

// ---------- pack ea rows to fp16 half2 dwords (9 used + 3 pad) ----------
__global__ void k_pack_ea(const float* __restrict__ ea, uint32_t* __restrict__ eah) {
    int t = blockIdx.x * blockDim.x + threadIdx.x;
    if (t >= EE * EAW) return;
    int e = t / EAW, kk = t - e * EAW;
    uint32_t v = 0;
    if (kk < 9) {
        float2 q = *(const float2*)(ea + (size_t)e * 18 + 2 * kk);
        v = packh2(q.x, q.y);
    }
    eah[t] = v;
}

// ---------- degree histogram ----------
__global__ void k_hist(const int* __restrict__ dst, int* __restrict__ hist) {
    int e = blockIdx.x * blockDim.x + threadIdx.x;
    if (e < EE) atomicAdd(&hist[dst[e]], 1);
}

// ---------- CSR build: scan of hist then scatter (real edges only) ----------
__global__ void k_scan_a(const int* __restrict__ hist, int* __restrict__ bsum) {
    __shared__ int tmp[256];
    int i = blockIdx.x * 256 + threadIdx.x;
    tmp[threadIdx.x] = (i < NN) ? hist[i] : 0;
    __syncthreads();
    for (int d = 128; d; d >>= 1) {
        if (threadIdx.x < d) tmp[threadIdx.x] += tmp[threadIdx.x + d];
        __syncthreads();
    }
    if (threadIdx.x == 0) bsum[blockIdx.x] = tmp[0];
}

__global__ void k_scan_b(int* __restrict__ bsum, int* __restrict__ rowptr) {
    int acc = 0;
    for (int b = 0; b < NB; b++) { int v = bsum[b]; bsum[b] = acc; acc += v; }
    rowptr[NN] = acc;  // == EE
}

__global__ void k_scan_c(const int* __restrict__ hist, const int* __restrict__ bsum,
                         int* __restrict__ rowptr) {
    __shared__ int tmp[256];
    int i = blockIdx.x * 256 + threadIdx.x;
    int v = (i < NN) ? hist[i] : 0;
    tmp[threadIdx.x] = v;
    __syncthreads();
    for (int d = 1; d < 256; d <<= 1) {
        int t = (threadIdx.x >= d) ? tmp[threadIdx.x - d] : 0;
        __syncthreads();
        tmp[threadIdx.x] += t;
        __syncthreads();
    }
    if (i < NN) rowptr[i] = tmp[threadIdx.x] - v + bsum[blockIdx.x];
}

__global__ void k_cursor_init(const int* __restrict__ rowptr, int* __restrict__ cursor) {
    int i = blockIdx.x * blockDim.x + threadIdx.x;
    if (i < NN) cursor[i] = rowptr[i];
}

__global__ void k_scatter(const int* __restrict__ dst, int* __restrict__ cursor,
                          int* __restrict__ csr_eid) {
    int e = blockIdx.x * blockDim.x + threadIdx.x;
    if (e < EE) {
        int p = atomicAdd(&cursor[dst[e]], 1);
        csr_eid[p] = e;
    }
}

// ---------- fused dual node-linear: xl = X@Wl+bl ; xr = X@Wr+br ----------
__global__ void k_dual_linear(const float* __restrict__ X,
                              const float* __restrict__ Wl, const float* __restrict__ bl,
                              const float* __restrict__ Wr, const float* __restrict__ br,
                              float* __restrict__ xl, float* __restrict__ xr,
                              int Cin, int Cout) {
    int t = blockIdx.x * blockDim.x + threadIdx.x;
    if (t >= NN * Cout) return;
    int i = t / Cout, j = t - i * Cout;
    const float* xrow = X + (size_t)i * Cin;
    float al = bl[j], ar = br[j];
    for (int k = 0; k < Cin; k++) {
        float xv = xrow[k];
        al += xv * Wl[k * Cout + j];
        ar += xv * Wr[k * Cout + j];
    }
    xl[t] = al;
    xr[t] = ar;
}

// ---------- fused per-dst-node: scores + online softmax + aggregate ----------
// Wave per node. Lane l (< C/VEC) owns channels [l*VEC, l*VEC+VEC).
// ea@We via fp16 dot2 (packed ea rows, uniform vector loads -> VGPRs).
// Edge ids/srcs loaded cooperatively per 64-chunk, broadcast via readlane.
// Self-loop edge-attr = mean of incoming ea -> mean of per-edge ea@We (wsum).
template <int C, int VEC, int RELU>
__global__ void __launch_bounds__(256, 2)
k_fused_node(const int* __restrict__ rowptr, const int* __restrict__ csr_eid,
             const int* __restrict__ srcv, const uint32_t* __restrict__ eah,
             const float* __restrict__ We, const float* __restrict__ att,
             const float* __restrict__ xl, const float* __restrict__ xr,
             const float* __restrict__ bias, float* __restrict__ out) {
    constexpr int NL = C / VEC;
    const int lane = threadIdx.x & 63;
    int wid = blockIdx.x * (blockDim.x >> 6) + (threadIdx.x >> 6);
    int nw = gridDim.x * (blockDim.x >> 6);
    const bool act = lane < NL;

    uint32_t Wfp[9][VEC];
    float af[VEC], bv[VEC];
    if (act) {
#pragma unroll
        for (int kk = 0; kk < 9; kk++)
#pragma unroll
            for (int j = 0; j < VEC; j++) {
                int col = lane * VEC + j;
                Wfp[kk][j] = packh2(We[(2 * kk) * C + col], We[(2 * kk + 1) * C + col]);
            }
#pragma unroll
        for (int j = 0; j < VEC; j++) { af[j] = att[lane * VEC + j]; bv[j] = bias[lane * VEC + j]; }
    } else {
#pragma unroll
        for (int kk = 0; kk < 9; kk++)
#pragma unroll
            for (int j = 0; j < VEC; j++) Wfp[kk][j] = 0;
#pragma unroll
        for (int j = 0; j < VEC; j++) { af[j] = 0.f; bv[j] = 0.f; }
    }

    for (int i = wid; i < NN; i += nw) {
        int beg = __builtin_amdgcn_readfirstlane(rowptr[i]);
        int end = __builtin_amdgcn_readfirstlane(rowptr[i + 1]);

        float xlv[VEC], xrv[VEC];
        if (act) {
            if constexpr (VEC == 4) {
                float4 a = *(const float4*)(xl + (size_t)i * C + lane * 4);
                xlv[0] = a.x; xlv[1] = a.y; xlv[2] = a.z; xlv[3] = a.w;
                float4 b = *(const float4*)(xr + (size_t)i * C + lane * 4);
                xrv[0] = b.x; xrv[1] = b.y; xrv[2] = b.z; xrv[3] = b.w;
            } else {
                float2 a = *(const float2*)(xl + (size_t)i * C + lane * 2);
                xlv[0] = a.x; xlv[1] = a.y;
                float2 b = *(const float2*)(xr + (size_t)i * C + lane * 2);
                xrv[0] = b.x; xrv[1] = b.y;
            }
        } else {
#pragma unroll
            for (int j = 0; j < VEC; j++) { xlv[j] = 0.f; xrv[j] = 0.f; }
        }

        float m = -INFINITY, zs = 0.0f;
        float acc[VEC], wsum[VEC];
#pragma unroll
        for (int j = 0; j < VEC; j++) { acc[j] = 0.f; wsum[j] = 0.f; }

        for (int cs = beg; cs < end; cs += 64) {
            int cnt = end - cs; if (cnt > 64) cnt = 64;
            // cooperative: 64 edge ids coalesced + 64 src gathers in parallel
            int eid_l = 0, src_l = 0;
            if (lane < cnt) {
                eid_l = csr_eid[cs + lane];
                src_l = srcv[eid_l];
            }

            // preload edge 0 of chunk
            uint32_t ean[9];
            float xvn[VEC];
#pragma unroll
            for (int j = 0; j < VEC; j++) xvn[j] = 0.f;
            {
                int e0 = __builtin_amdgcn_readlane(eid_l, 0);
                int s0 = __builtin_amdgcn_readlane(src_l, 0);
                const uint32_t* ep = eah + (size_t)e0 * EAW;
                uint4 q0 = *(const uint4*)ep;
                uint4 q1 = *(const uint4*)(ep + 4);
                ean[0] = q0.x; ean[1] = q0.y; ean[2] = q0.z; ean[3] = q0.w;
                ean[4] = q1.x; ean[5] = q1.y; ean[6] = q1.z; ean[7] = q1.w;
                ean[8] = ep[8];
                if (act) {
                    if constexpr (VEC == 4) {
                        float4 v = *(const float4*)(xl + (size_t)s0 * C + lane * 4);
                        xvn[0] = v.x; xvn[1] = v.y; xvn[2] = v.z; xvn[3] = v.w;
                    } else {
                        float2 v = *(const float2*)(xl + (size_t)s0 * C + lane * 2);
                        xvn[0] = v.x; xvn[1] = v.y;
                    }
                }
            }

            for (int t = 0; t < cnt; t++) {
                uint32_t eac[9];
                float xv[VEC];
#pragma unroll
                for (int kk = 0; kk < 9; kk++) eac[kk] = ean[kk];
#pragma unroll
                for (int j = 0; j < VEC; j++) xv[j] = xvn[j];

                if (t + 1 < cnt) {
                    int e1 = __builtin_amdgcn_readlane(eid_l, t + 1);
                    int s1 = __builtin_amdgcn_readlane(src_l, t + 1);
                    const uint32_t* ep = eah + (size_t)e1 * EAW;
                    uint4 q0 = *(const uint4*)ep;
                    uint4 q1 = *(const uint4*)(ep + 4);
                    ean[0] = q0.x; ean[1] = q0.y; ean[2] = q0.z; ean[3] = q0.w;
                    ean[4] = q1.x; ean[5] = q1.y; ean[6] = q1.z; ean[7] = q1.w;
                    ean[8] = ep[8];
                    if (act) {
                        if constexpr (VEC == 4) {
                            float4 v = *(const float4*)(xl + (size_t)s1 * C + lane * 4);
                            xvn[0] = v.x; xvn[1] = v.y; xvn[2] = v.z; xvn[3] = v.w;
                        } else {
                            float2 v = *(const float2*)(xl + (size_t)s1 * C + lane * 2);
                            xvn[0] = v.x; xvn[1] = v.y;
                        }
                    }
                }

                float part = 0.0f;
#pragma unroll
                for (int j = 0; j < VEC; j++) {
                    float w = 0.0f;
#pragma unroll
                    for (int kk = 0; kk < 9; kk++) w = fdot2u(eac[kk], Wfp[kk][j], w);
                    wsum[j] += w;
                    float u = xv[j] + xrv[j] + w;
                    float h = u > 0.0f ? u : NEG_SLOPE * u;
                    part += af[j] * h;
                }
#pragma unroll
                for (int off = 32; off; off >>= 1) part += __shfl_xor(part, off, 64);

                float mn = fmaxf(m, part);
                float sc = __expf(m - mn);
                float pe = __expf(part - mn);
                zs = zs * sc + pe;
                m = mn;
#pragma unroll
                for (int j = 0; j < VEC; j++) acc[j] = acc[j] * sc + pe * xv[j];
            }
        }

        // self-loop (order-invariant under online softmax)
        {
            float rdeg = (end > beg) ? 1.0f / (float)(end - beg) : 1.0f;
            float part = 0.0f;
#pragma unroll
            for (int j = 0; j < VEC; j++) {
                float u = xlv[j] + xrv[j] + wsum[j] * rdeg;
                float h = u > 0.0f ? u : NEG_SLOPE * u;
                part += af[j] * h;
            }
#pragma unroll
            for (int off = 32; off; off >>= 1) part += __shfl_xor(part, off, 64);

            float mn = fmaxf(m, part);
            float sc = __expf(m - mn);
            float pe = __expf(part - mn);
            zs = zs * sc + pe;
#pragma unroll
            for (int j = 0; j < VEC; j++) acc[j] = acc[j] * sc + pe * xlv[j];
        }

        float rz = 1.0f / zs;
        if (act) {
            float o[VEC];
#pragma unroll
            for (int j = 0; j < VEC; j++) {
                o[j] = acc[j] * rz + bv[j];
                if (RELU) o[j] = fmaxf(o[j], 0.0f);
            }
            if constexpr (VEC == 4) {
                *(float4*)(out + (size_t)i * C + lane * 4) = make_float4(o[0], o[1], o[2], o[3]);
            } else {
                *(float2*)(out + (size_t)i * C + lane * 2) = make_float2(o[0], o[1]);
            }
        }
    }
}

// ---------- mean pooling per graph (batch_ids sorted); relu folded in ----------
__global__ void k_pool(const float* __restrict__ h, const int* __restrict__ batch,
                       float* __restrict__ pooled) {
    int g = blockIdx.x;
    int lo = 0, hi = NN;
    while (lo < hi) { int mid = (lo + hi) >> 1; if (batch[mid] < g) lo = mid + 1; else hi = mid; }
    int start = lo;
    lo = start; hi = NN;
    while (lo < hi) { int mid = (lo + hi) >> 1; if (batch[mid] < g + 1) lo = mid + 1; else hi = mid; }
    int end = lo;
    float cnt = (float)(end - start);
    int c = threadIdx.x;
    if (c < 200) {
        float acc = 0.0f;
        for (int i = start; i < end; i++) acc += fmaxf(h[(size_t)i * 200 + c], 0.0f);
        pooled[g * 200 + c] = acc / fmaxf(cnt, 1.0f);
    }
}

// ---------- small dense layers on [G, *] ----------
__global__ void k_mlp(const float* __restrict__ X, const float* __restrict__ W,
                      const float* __restrict__ b, float* __restrict__ Y,
                      int Cin, int Cout, int do_relu) {
    int t = blockIdx.x * blockDim.x + threadIdx.x;
    if (t >= GG * Cout) return;
    int g = t / Cout, j = t - g * Cout;
    const float* xrow = X + (size_t)g * Cin;
    float acc = b[j];
    for (int k = 0; k < Cin; k++) acc += xrow[k] * W[k * Cout + j];
    if (do_relu) acc = fmaxf(acc, 0.0f);
    Y[t] = acc;
}

extern "C" void kernel_launch(void* const* d_in, const int* in_sizes, int n_in,
                              void* d_out, int out_size, void* d_ws, size_t ws_size,
                              hipStream_t stream) {
    const float* x   = (const float*)d_in[0];
    const int*   ei  = (const int*)d_in[1];
    const float* ea  = (const float*)d_in[2];
    const int*   bat = (const int*)d_in[3];
    const float* W1l = (const float*)d_in[4];  const float* b1l = (const float*)d_in[5];
    const float* W1r = (const float*)d_in[6];  const float* b1r = (const float*)d_in[7];
    const float* W1e = (const float*)d_in[8];
    const float* a1  = (const float*)d_in[9];  const float* c1  = (const float*)d_in[10];
    const float* W2l = (const float*)d_in[11]; const float* b2l = (const float*)d_in[12];
    const float* W2r = (const float*)d_in[13]; const float* b2r = (const float*)d_in[14];
    const float* W2e = (const float*)d_in[15];
    const float* a2  = (const float*)d_in[16]; const float* c2  = (const float*)d_in[17];
    const float* W3  = (const float*)d_in[18]; const float* b3  = (const float*)d_in[19];
    const float* F1  = (const float*)d_in[20]; const float* bf1 = (const float*)d_in[21];
    const float* F2  = (const float*)d_in[22]; const float* bf2 = (const float*)d_in[23];
    const float* F3  = (const float*)d_in[24]; const float* bf3 = (const float*)d_in[25];

    const int* srcv = ei;        // edge_index[0]
    const int* dstv = ei + EE;   // edge_index[1]

    float* W = (float*)d_ws;
    size_t off = 0;
    int*      hist    = (int*)(W + off); off += NN;
    float*    xl      = W + off; off += (size_t)NN * 200;
    float*    xr      = W + off; off += (size_t)NN * 200;
    float*    h1      = W + off; off += (size_t)NN * 100;
    float*    h2      = W + off; off += (size_t)NN * 200;
    int*      rowptr  = (int*)(W + off); off += NN + 4;
    int*      cursor  = (int*)(W + off); off += NN;
    int*      csr_eid = (int*)(W + off); off += EE;
    int*      bsum    = (int*)(W + off); off += 256;
    uint32_t* eah     = (uint32_t*)(W + off); off += (size_t)EE * EAW;
    float*    pooled  = W + off; off += (size_t)GG * 200;
    float*    p400    = W + off; off += (size_t)GG * 400;
    float*    y1      = W + off; off += (size_t)GG * 200;
    float*    y2      = W + off; off += (size_t)GG * 100;
    (void)ws_size; (void)n_in; (void)in_sizes; (void)out_size;

    const int B = 256;
    const int NODEB = 12500;   // 4 waves/block -> 50000 waves, 1 node each

    // ---- pack ea to fp16 ----
    k_pack_ea<<<((size_t)EE * EAW + B - 1) / B, B, 0, stream>>>(ea, eah);

    // ---- degree histogram + CSR by dst (real edges only) ----
    hipMemsetAsync(hist, 0, (size_t)NN * sizeof(int), stream);
    k_hist<<<(EE + B - 1) / B, B, 0, stream>>>(dstv, hist);
    k_scan_a<<<NB, 256, 0, stream>>>(hist, bsum);
    k_scan_b<<<1, 1, 0, stream>>>(bsum, rowptr);
    k_scan_c<<<NB, 256, 0, stream>>>(hist, bsum, rowptr);
    k_cursor_init<<<(NN + B - 1) / B, B, 0, stream>>>(rowptr, cursor);
    k_scatter<<<(EE + B - 1) / B, B, 0, stream>>>(dstv, cursor, csr_eid);

    // ---- GAT layer 1: 16 -> 100 ----
    k_dual_linear<<<((size_t)NN * 100 + B - 1) / B, B, 0, stream>>>(x, W1l, b1l, W1r, b1r, xl, xr, 16, 100);
    k_fused_node<100, 2, 1><<<NODEB, B, 0, stream>>>(rowptr, csr_eid, srcv, eah, W1e, a1, xl, xr, c1, h1);

    // ---- GAT layer 2: 100 -> 200 ----
    k_dual_linear<<<((size_t)NN * 200 + B - 1) / B, B, 0, stream>>>(h1, W2l, b2l, W2r, b2r, xl, xr, 100, 200);
    k_fused_node<200, 4, 0><<<NODEB, B, 0, stream>>>(rowptr, csr_eid, srcv, eah, W2e, a2, xl, xr, c2, h2);

    // ---- pool (mean over graph, relu fused) then W3 + FFN ----
    k_pool<<<GG, 256, 0, stream>>>(h2, bat, pooled);
    k_mlp<<<(GG * 400 + B - 1) / B, B, 0, stream>>>(pooled, W3, b3, p400, 200, 400, 0);
    k_mlp<<<(GG * 200 + B - 1) / B, B, 0, stream>>>(p400, F1, bf1, y1, 400, 200, 1);
    k_mlp<<<(GG * 100 + B - 1) / B, B, 0, stream>>>(y1, F2, bf2, y2, 200, 100, 1);
    k_mlp<<<(GG * 100 + B - 1) / B, B, 0, stream>>>(y2, F3, bf3, (float*)d_out, 100, 100, 0);
}

// Round 7
// 1544.285 us; speedup vs baseline: 4.4265x; 1.2597x over previous
//
#include <hip/hip_runtime.h>
#include <cstdint>
#include <climits>
#include <math.h>

#define NN 50000
#define EE 1600000
#define GG 512
#define NEG_SLOPE 0.2f
#define NB 196          // ceil(NN/256) scan blocks
#define EAW 12          // padded dwords per packed-fp16 ea row (48 B, 16B-aligned)

typedef _Float16 half2v __attribute__((ext_vector_type(2)));

__device__ __forceinline__ uint32_t packh2(float a, float b) {
    union { half2v h; uint32_t u; } c;
    c.h = half2v{(_Float16)a, (_Float16)b};
    return c.u;
}
__device__ __forceinline__ float fdot2u(uint32_t a, uint32_t b, float c) {
    union { uint32_t u; half2v h; } ua, ub;
    ua.u = a; ub.u = b;
    return __builtin_amdgcn_fdot2(ua.h, ub.h, c, false);
}

// ---------- pack ea rows to fp16 half2 dwords (9 used + 3 pad) ----------
__global__ void k_pack_ea(const float* __restrict__ ea, uint32_t* __restrict__ eah) {
    int t = blockIdx.x * blockDim.x + threadIdx.x;
    if (t >= EE * EAW) return;
    int e = t / EAW, kk = t - e * EAW;
    uint32_t v = 0;
    if (kk < 9) {
        float2 q = *(const float2*)(ea + (size_t)e * 18 + 2 * kk);
        v = packh2(q.x, q.y);
    }
    eah[t] = v;
}

// ---------- degree histogram ----------
__global__ void k_hist(const int* __restrict__ dst, int* __restrict__ hist) {
    int e = blockIdx.x * blockDim.x + threadIdx.x;
    if (e < EE) atomicAdd(&hist[dst[e]], 1);
}

// ---------- CSR build: scan of hist then scatter (real edges only) ----------
__global__ void k_scan_a(const int* __restrict__ hist, int* __restrict__ bsum) {
    __shared__ int tmp[256];
    int i = blockIdx.x * 256 + threadIdx.x;
    tmp[threadIdx.x] = (i < NN) ? hist[i] : 0;
    __syncthreads();
    for (int d = 128; d; d >>= 1) {
        if (threadIdx.x < d) tmp[threadIdx.x] += tmp[threadIdx.x + d];
        __syncthreads();
    }
    if (threadIdx.x == 0) bsum[blockIdx.x] = tmp[0];
}

__global__ void k_scan_b(int* __restrict__ bsum, int* __restrict__ rowptr) {
    int acc = 0;
    for (int b = 0; b < NB; b++) { int v = bsum[b]; bsum[b] = acc; acc += v; }
    rowptr[NN] = acc;  // == EE
}

__global__ void k_scan_c(const int* __restrict__ hist, const int* __restrict__ bsum,
                         int* __restrict__ rowptr) {
    __shared__ int tmp[256];
    int i = blockIdx.x * 256 + threadIdx.x;
    int v = (i < NN) ? hist[i] : 0;
    tmp[threadIdx.x] = v;
    __syncthreads();
    for (int d = 1; d < 256; d <<= 1) {
        int t = (threadIdx.x >= d) ? tmp[threadIdx.x - d] : 0;
        __syncthreads();
        tmp[threadIdx.x] += t;
        __syncthreads();
    }
    if (i < NN) rowptr[i] = tmp[threadIdx.x] - v + bsum[blockIdx.x];
}

__global__ void k_cursor_init(const int* __restrict__ rowptr, int* __restrict__ cursor) {
    int i = blockIdx.x * blockDim.x + threadIdx.x;
    if (i < NN) cursor[i] = rowptr[i];
}

__global__ void k_scatter(const int* __restrict__ dst, int* __restrict__ cursor,
                          int* __restrict__ csr_eid) {
    int e = blockIdx.x * blockDim.x + threadIdx.x;
    if (e < EE) {
        int p = atomicAdd(&cursor[dst[e]], 1);
        csr_eid[p] = e;
    }
}

// ---------- combine Wl|Wr into padded Wc [K x NP], biases into bc [NP] ----------
__global__ void k_combine_w(const float* __restrict__ Wl, const float* __restrict__ bl,
                            const float* __restrict__ Wr, const float* __restrict__ br,
                            float* __restrict__ Wc, float* __restrict__ bc,
                            int K, int C, int NP) {
    int t = blockIdx.x * blockDim.x + threadIdx.x;
    if (t < K * NP) {
        int k = t / NP, n = t - k * NP;
        float v = 0.0f;
        if (n < C) v = Wl[k * C + n];
        else if (n < 2 * C) v = Wr[k * C + n - C];
        Wc[t] = v;
    }
    if (t < NP) {
        float v = 0.0f;
        if (t < C) v = bl[t];
        else if (t < 2 * C) v = br[t - C];
        bc[t] = v;
    }
}

// ---------- tiled dual GEMM: [NN x K] @ Wc[K x NP] -> xl|xr (cols 0..C-1 / C..2C-1) ----------
// BM=64, BN=64, BK=16, 256 threads, 4x4 micro-tile.
template <int KK, int NP, int C>
__global__ void __launch_bounds__(256)
k_gemm_dual(const float* __restrict__ A, const float* __restrict__ Wc,
            const float* __restrict__ bc, float* __restrict__ xl, float* __restrict__ xr) {
    constexpr int BM = 64, BN = 64, BK = 16;
    __shared__ float As[BK][BM];   // transposed A tile
    __shared__ float Ws[BK][BN];
    const int tidx = threadIdx.x;
    const int tx = tidx & 15;      // N dir
    const int ty = tidx >> 4;      // M dir
    const int m0 = blockIdx.x * BM;
    const int n0 = blockIdx.y * BN;

    float acc[4][4];
#pragma unroll
    for (int i2 = 0; i2 < 4; i2++)
#pragma unroll
        for (int j2 = 0; j2 < 4; j2++) acc[i2][j2] = 0.0f;

    for (int k0 = 0; k0 < KK; k0 += BK) {
        // stage A (transpose): 64 rows x 16 k
        {
            int m = tidx >> 2;
            int kq = (tidx & 3) * 4;
            float4 v = make_float4(0.f, 0.f, 0.f, 0.f);
            if (m0 + m < NN && k0 + kq < KK)
                v = *(const float4*)(A + (size_t)(m0 + m) * KK + k0 + kq);
            As[kq + 0][m] = v.x; As[kq + 1][m] = v.y;
            As[kq + 2][m] = v.z; As[kq + 3][m] = v.w;
        }
        // stage W: 16 k x 64 n
        {
            int k = tidx >> 4;
            int nq = (tidx & 15) * 4;
            float4 v = make_float4(0.f, 0.f, 0.f, 0.f);
            if (k0 + k < KK)
                v = *(const float4*)(Wc + (size_t)(k0 + k) * NP + n0 + nq);
            *(float4*)&Ws[k][nq] = v;
        }
        __syncthreads();
#pragma unroll
        for (int k = 0; k < BK; k++) {
            float a[4], b[4];
            *(float4*)a = *(const float4*)&As[k][ty * 4];
            *(float4*)b = *(const float4*)&Ws[k][tx * 4];
#pragma unroll
            for (int i2 = 0; i2 < 4; i2++)
#pragma unroll
                for (int j2 = 0; j2 < 4; j2++) acc[i2][j2] += a[i2] * b[j2];
        }
        __syncthreads();
    }

    const int n = n0 + tx * 4;
    float4 bcv = *(const float4*)(bc + n);
#pragma unroll
    for (int i2 = 0; i2 < 4; i2++) {
        int m = m0 + ty * 4 + i2;
        if (m >= NN) continue;
        float4 o = make_float4(acc[i2][0] + bcv.x, acc[i2][1] + bcv.y,
                               acc[i2][2] + bcv.z, acc[i2][3] + bcv.w);
        if (n < C)            *(float4*)(xl + (size_t)m * C + n) = o;
        else if (n < 2 * C)   *(float4*)(xr + (size_t)m * C + n - C) = o;
    }
}

// ---------- fused per-dst-node: scores + online softmax + aggregate ----------
template <int C, int VEC, int RELU>
__global__ void __launch_bounds__(256, 2)
k_fused_node(const int* __restrict__ rowptr, const int* __restrict__ csr_eid,
             const int* __restrict__ srcv, const uint32_t* __restrict__ eah,
             const float* __restrict__ We, const float* __restrict__ att,
             const float* __restrict__ xl, const float* __restrict__ xr,
             const float* __restrict__ bias, float* __restrict__ out) {
    constexpr int NL = C / VEC;
    const int lane = threadIdx.x & 63;
    int wid = blockIdx.x * (blockDim.x >> 6) + (threadIdx.x >> 6);
    int nw = gridDim.x * (blockDim.x >> 6);
    const bool act = lane < NL;

    uint32_t Wfp[9][VEC];
    float af[VEC], bv[VEC];
    if (act) {
#pragma unroll
        for (int kk = 0; kk < 9; kk++)
#pragma unroll
            for (int j = 0; j < VEC; j++) {
                int col = lane * VEC + j;
                Wfp[kk][j] = packh2(We[(2 * kk) * C + col], We[(2 * kk + 1) * C + col]);
            }
#pragma unroll
        for (int j = 0; j < VEC; j++) { af[j] = att[lane * VEC + j]; bv[j] = bias[lane * VEC + j]; }
    } else {
#pragma unroll
        for (int kk = 0; kk < 9; kk++)
#pragma unroll
            for (int j = 0; j < VEC; j++) Wfp[kk][j] = 0;
#pragma unroll
        for (int j = 0; j < VEC; j++) { af[j] = 0.f; bv[j] = 0.f; }
    }

    for (int i = wid; i < NN; i += nw) {
        int beg = __builtin_amdgcn_readfirstlane(rowptr[i]);
        int end = __builtin_amdgcn_readfirstlane(rowptr[i + 1]);

        float xlv[VEC], xrv[VEC];
        if (act) {
            if constexpr (VEC == 4) {
                float4 a = *(const float4*)(xl + (size_t)i * C + lane * 4);
                xlv[0] = a.x; xlv[1] = a.y; xlv[2] = a.z; xlv[3] = a.w;
                float4 b = *(const float4*)(xr + (size_t)i * C + lane * 4);
                xrv[0] = b.x; xrv[1] = b.y; xrv[2] = b.z; xrv[3] = b.w;
            } else {
                float2 a = *(const float2*)(xl + (size_t)i * C + lane * 2);
                xlv[0] = a.x; xlv[1] = a.y;
                float2 b = *(const float2*)(xr + (size_t)i * C + lane * 2);
                xrv[0] = b.x; xrv[1] = b.y;
            }
        } else {
#pragma unroll
            for (int j = 0; j < VEC; j++) { xlv[j] = 0.f; xrv[j] = 0.f; }
        }

        float m = -INFINITY, zs = 0.0f;
        float acc[VEC], wsum[VEC];
#pragma unroll
        for (int j = 0; j < VEC; j++) { acc[j] = 0.f; wsum[j] = 0.f; }

        for (int cs = beg; cs < end; cs += 64) {
            int cnt = end - cs; if (cnt > 64) cnt = 64;
            int eid_l = 0, src_l = 0;
            if (lane < cnt) {
                eid_l = csr_eid[cs + lane];
                src_l = srcv[eid_l];
            }

            uint32_t ean[9];
            float xvn[VEC];
#pragma unroll
            for (int j = 0; j < VEC; j++) xvn[j] = 0.f;
            {
                int e0 = __builtin_amdgcn_readlane(eid_l, 0);
                int s0 = __builtin_amdgcn_readlane(src_l, 0);
                const uint32_t* ep = eah + (size_t)e0 * EAW;
                uint4 q0 = *(const uint4*)ep;
                uint4 q1 = *(const uint4*)(ep + 4);
                ean[0] = q0.x; ean[1] = q0.y; ean[2] = q0.z; ean[3] = q0.w;
                ean[4] = q1.x; ean[5] = q1.y; ean[6] = q1.z; ean[7] = q1.w;
                ean[8] = ep[8];
                if (act) {
                    if constexpr (VEC == 4) {
                        float4 v = *(const float4*)(xl + (size_t)s0 * C + lane * 4);
                        xvn[0] = v.x; xvn[1] = v.y; xvn[2] = v.z; xvn[3] = v.w;
                    } else {
                        float2 v = *(const float2*)(xl + (size_t)s0 * C + lane * 2);
                        xvn[0] = v.x; xvn[1] = v.y;
                    }
                }
            }

            for (int t = 0; t < cnt; t++) {
                uint32_t eac[9];
                float xv[VEC];
#pragma unroll
                for (int kk = 0; kk < 9; kk++) eac[kk] = ean[kk];
#pragma unroll
                for (int j = 0; j < VEC; j++) xv[j] = xvn[j];

                if (t + 1 < cnt) {
                    int e1 = __builtin_amdgcn_readlane(eid_l, t + 1);
                    int s1 = __builtin_amdgcn_readlane(src_l, t + 1);
                    const uint32_t* ep = eah + (size_t)e1 * EAW;
                    uint4 q0 = *(const uint4*)ep;
                    uint4 q1 = *(const uint4*)(ep + 4);
                    ean[0] = q0.x; ean[1] = q0.y; ean[2] = q0.z; ean[3] = q0.w;
                    ean[4] = q1.x; ean[5] = q1.y; ean[6] = q1.z; ean[7] = q1.w;
                    ean[8] = ep[8];
                    if (act) {
                        if constexpr (VEC == 4) {
                            float4 v = *(const float4*)(xl + (size_t)s1 * C + lane * 4);
                            xvn[0] = v.x; xvn[1] = v.y; xvn[2] = v.z; xvn[3] = v.w;
                        } else {
                            float2 v = *(const float2*)(xl + (size_t)s1 * C + lane * 2);
                            xvn[0] = v.x; xvn[1] = v.y;
                        }
                    }
                }

                float part = 0.0f;
#pragma unroll
                for (int j = 0; j < VEC; j++) {
                    float w = 0.0f;
#pragma unroll
                    for (int kk = 0; kk < 9; kk++) w = fdot2u(eac[kk], Wfp[kk][j], w);
                    wsum[j] += w;
                    float u = xv[j] + xrv[j] + w;
                    float h = u > 0.0f ? u : NEG_SLOPE * u;
                    part += af[j] * h;
                }
#pragma unroll
                for (int off = 32; off; off >>= 1) part += __shfl_xor(part, off, 64);

                float mn = fmaxf(m, part);
                float sc = __expf(m - mn);
                float pe = __expf(part - mn);
                zs = zs * sc + pe;
                m = mn;
#pragma unroll
                for (int j = 0; j < VEC; j++) acc[j] = acc[j] * sc + pe * xv[j];
            }
        }

        // self-loop (order-invariant under online softmax)
        {
            float rdeg = (end > beg) ? 1.0f / (float)(end - beg) : 1.0f;
            float part = 0.0f;
#pragma unroll
            for (int j = 0; j < VEC; j++) {
                float u = xlv[j] + xrv[j] + wsum[j] * rdeg;
                float h = u > 0.0f ? u : NEG_SLOPE * u;
                part += af[j] * h;
            }
#pragma unroll
            for (int off = 32; off; off >>= 1) part += __shfl_xor(part, off, 64);

            float mn = fmaxf(m, part);
            float sc = __expf(m - mn);
            float pe = __expf(part - mn);
            zs = zs * sc + pe;
#pragma unroll
            for (int j = 0; j < VEC; j++) acc[j] = acc[j] * sc + pe * xlv[j];
        }

        float rz = 1.0f / zs;
        if (act) {
            float o[VEC];
#pragma unroll
            for (int j = 0; j < VEC; j++) {
                o[j] = acc[j] * rz + bv[j];
                if (RELU) o[j] = fmaxf(o[j], 0.0f);
            }
            if constexpr (VEC == 4) {
                *(float4*)(out + (size_t)i * C + lane * 4) = make_float4(o[0], o[1], o[2], o[3]);
            } else {
                *(float2*)(out + (size_t)i * C + lane * 2) = make_float2(o[0], o[1]);
            }
        }
    }
}

// ---------- mean pooling per graph (batch_ids sorted); relu folded in ----------
__global__ void k_pool(const float* __restrict__ h, const int* __restrict__ batch,
                       float* __restrict__ pooled) {
    int g = blockIdx.x;
    int lo = 0, hi = NN;
    while (lo < hi) { int mid = (lo + hi) >> 1; if (batch[mid] < g) lo = mid + 1; else hi = mid; }
    int start = lo;
    lo = start; hi = NN;
    while (lo < hi) { int mid = (lo + hi) >> 1; if (batch[mid] < g + 1) lo = mid + 1; else hi = mid; }
    int end = lo;
    float cnt = (float)(end - start);
    int c = threadIdx.x;
    if (c < 200) {
        float acc = 0.0f;
        for (int i = start; i < end; i++) acc += fmaxf(h[(size_t)i * 200 + c], 0.0f);
        pooled[g * 200 + c] = acc / fmaxf(cnt, 1.0f);
    }
}

// ---------- small dense layers on [G, *] ----------
__global__ void k_mlp(const float* __restrict__ X, const float* __restrict__ W,
                      const float* __restrict__ b, float* __restrict__ Y,
                      int Cin, int Cout, int do_relu) {
    int t = blockIdx.x * blockDim.x + threadIdx.x;
    if (t >= GG * Cout) return;
    int g = t / Cout, j = t - g * Cout;
    const float* xrow = X + (size_t)g * Cin;
    float acc = b[j];
    for (int k = 0; k < Cin; k++) acc += xrow[k] * W[k * Cout + j];
    if (do_relu) acc = fmaxf(acc, 0.0f);
    Y[t] = acc;
}

extern "C" void kernel_launch(void* const* d_in, const int* in_sizes, int n_in,
                              void* d_out, int out_size, void* d_ws, size_t ws_size,
                              hipStream_t stream) {
    const float* x   = (const float*)d_in[0];
    const int*   ei  = (const int*)d_in[1];
    const float* ea  = (const float*)d_in[2];
    const int*   bat = (const int*)d_in[3];
    const float* W1l = (const float*)d_in[4];  const float* b1l = (const float*)d_in[5];
    const float* W1r = (const float*)d_in[6];  const float* b1r = (const float*)d_in[7];
    const float* W1e = (const float*)d_in[8];
    const float* a1  = (const float*)d_in[9];  const float* c1  = (const float*)d_in[10];
    const float* W2l = (const float*)d_in[11]; const float* b2l = (const float*)d_in[12];
    const float* W2r = (const float*)d_in[13]; const float* b2r = (const float*)d_in[14];
    const float* W2e = (const float*)d_in[15];
    const float* a2  = (const float*)d_in[16]; const float* c2  = (const float*)d_in[17];
    const float* W3  = (const float*)d_in[18]; const float* b3  = (const float*)d_in[19];
    const float* F1  = (const float*)d_in[20]; const float* bf1 = (const float*)d_in[21];
    const float* F2  = (const float*)d_in[22]; const float* bf2 = (const float*)d_in[23];
    const float* F3  = (const float*)d_in[24]; const float* bf3 = (const float*)d_in[25];

    const int* srcv = ei;        // edge_index[0]
    const int* dstv = ei + EE;   // edge_index[1]

    float* W = (float*)d_ws;
    size_t off = 0;
    int*      hist    = (int*)(W + off); off += NN;
    float*    xl      = W + off; off += (size_t)NN * 200;
    float*    xr      = W + off; off += (size_t)NN * 200;
    float*    h1      = W + off; off += (size_t)NN * 100;
    float*    h2      = W + off; off += (size_t)NN * 200;
    int*      rowptr  = (int*)(W + off); off += NN + 4;
    int*      cursor  = (int*)(W + off); off += NN;
    int*      csr_eid = (int*)(W + off); off += EE;
    int*      bsum    = (int*)(W + off); off += 256;
    uint32_t* eah     = (uint32_t*)(W + off); off += (size_t)EE * EAW;
    float*    Wc1     = W + off; off += 16 * 256;
    float*    bc1     = W + off; off += 256;
    float*    Wc2     = W + off; off += 100 * 448;
    float*    bc2     = W + off; off += 448;
    float*    pooled  = W + off; off += (size_t)GG * 200;
    float*    p400    = W + off; off += (size_t)GG * 400;
    float*    y1      = W + off; off += (size_t)GG * 200;
    float*    y2      = W + off; off += (size_t)GG * 100;
    (void)ws_size; (void)n_in; (void)in_sizes; (void)out_size;

    const int B = 256;
    const int NODEB = 12500;   // 4 waves/block -> 50000 waves, 1 node each

    // ---- pack ea to fp16 ----
    k_pack_ea<<<((size_t)EE * EAW + B - 1) / B, B, 0, stream>>>(ea, eah);

    // ---- degree histogram + CSR by dst (real edges only) ----
    hipMemsetAsync(hist, 0, (size_t)NN * sizeof(int), stream);
    k_hist<<<(EE + B - 1) / B, B, 0, stream>>>(dstv, hist);
    k_scan_a<<<NB, 256, 0, stream>>>(hist, bsum);
    k_scan_b<<<1, 1, 0, stream>>>(bsum, rowptr);
    k_scan_c<<<NB, 256, 0, stream>>>(hist, bsum, rowptr);
    k_cursor_init<<<(NN + B - 1) / B, B, 0, stream>>>(rowptr, cursor);
    k_scatter<<<(EE + B - 1) / B, B, 0, stream>>>(dstv, cursor, csr_eid);

    // ---- combined weight matrices ----
    k_combine_w<<<(16 * 256 + B - 1) / B, B, 0, stream>>>(W1l, b1l, W1r, b1r, Wc1, bc1, 16, 100, 256);
    k_combine_w<<<(100 * 448 + B - 1) / B, B, 0, stream>>>(W2l, b2l, W2r, b2r, Wc2, bc2, 100, 200, 448);

    // ---- GAT layer 1: 16 -> 100 ----
    {
        dim3 grid((NN + 63) / 64, 256 / 64);
        k_gemm_dual<16, 256, 100><<<grid, 256, 0, stream>>>(x, Wc1, bc1, xl, xr);
    }
    k_fused_node<100, 2, 1><<<NODEB, B, 0, stream>>>(rowptr, csr_eid, srcv, eah, W1e, a1, xl, xr, c1, h1);

    // ---- GAT layer 2: 100 -> 200 ----
    {
        dim3 grid((NN + 63) / 64, 448 / 64);
        k_gemm_dual<100, 448, 200><<<grid, 256, 0, stream>>>(h1, Wc2, bc2, xl, xr);
    }
    k_fused_node<200, 4, 0><<<NODEB, B, 0, stream>>>(rowptr, csr_eid, srcv, eah, W2e, a2, xl, xr, c2, h2);

    // ---- pool (mean over graph, relu fused) then W3 + FFN ----
    k_pool<<<GG, 256, 0, stream>>>(h2, bat, pooled);
    k_mlp<<<(GG * 400 + B - 1) / B, B, 0, stream>>>(pooled, W3, b3, p400, 200, 400, 0);
    k_mlp<<<(GG * 200 + B - 1) / B, B, 0, stream>>>(p400, F1, bf1, y1, 400, 200, 1);
    k_mlp<<<(GG * 100 + B - 1) / B, B, 0, stream>>>(y1, F2, bf2, y2, 200, 100, 1);
    k_mlp<<<(GG * 100 + B - 1) / B, B, 0, stream>>>(y2, F3, bf3, (float*)d_out, 100, 100, 0);
}